// Round 3
// baseline (72.840 us; speedup 1.0000x reference)
//
#include <hip/hip_runtime.h>
#include <math.h>

#define THRESH_ 0.95f

// ws layout (float units):
// [0, 16384)              wrec : [1024][16] floats — [0..7]=centered word, [8]=wstd, rest pad (64B records)
// [16384, 278528)         hcw  : [32768][8]  (pre-masked haar coeffs)
// [278528, 311296)        idxw : [32768] (int)

__global__ __launch_bounds__(256) void k0_vocab(const float* __restrict__ vocab,
                                                float* __restrict__ wrec) {
    int v = blockIdx.x * 256 + threadIdx.x;
    if (v >= 1024) return;
    const float4* v4 = (const float4*)vocab + v * 2;
    float4 a = v4[0], b = v4[1];
    float w[8] = {a.x, a.y, a.z, a.w, b.x, b.y, b.z, b.w};
    float s = 0.f;
#pragma unroll
    for (int c = 0; c < 8; c++) s += w[c];
    float mean = s * 0.125f;
    float ss = 0.f;
    float wcv[8];
#pragma unroll
    for (int c = 0; c < 8; c++) { wcv[c] = w[c] - mean; ss += wcv[c] * wcv[c]; }
    float sd = sqrtf(ss * 0.125f);
    float4 o0 = {wcv[0], wcv[1], wcv[2], wcv[3]};
    float4 o1 = {wcv[4], wcv[5], wcv[6], wcv[7]};
    float4* o = (float4*)(wrec + v * 16);
    o[0] = o0;
    o[1] = o1;
    wrec[v * 16 + 8] = sd;
}

// one block per batch row b; 1024 threads: t = part*128 + s  (part = v-chunk)
__global__ __launch_bounds__(1024) void k1_select(const float* __restrict__ X,
                                                  const float* __restrict__ wrec,
                                                  float* __restrict__ hcw,
                                                  int* __restrict__ idxw) {
    __shared__ float xrow[1024];
    __shared__ float stb[1024];
    __shared__ int   sti[1024];
    __shared__ float stm[1024];
    __shared__ float tree[254]; // sum8[128] | sum16[64]@128 | sum32[32]@192 | sum64[16]@224 | sum128[8]@240 | sum256[4]@248 | sum512[2]@252

    int t = threadIdx.x;
    int b = blockIdx.x;
    int part = t >> 7;
    int s = t & 127;

    xrow[t] = X[b * 1024 + t];
    __syncthreads();

    // segment stats (each of the 8 part-threads for segment s redundantly computes)
    float seg[8];
#pragma unroll
    for (int c = 0; c < 8; c++) seg[c] = xrow[s * 8 + c];
    float sum = 0.f;
#pragma unroll
    for (int c = 0; c < 8; c++) sum += seg[c];
    float mean = sum * 0.125f;
    float segc[8];
    float ss = 0.f;
#pragma unroll
    for (int c = 0; c < 8; c++) { segc[c] = seg[c] - mean; ss += segc[c] * segc[c]; }
    float sstd = sqrtf(ss * 0.125f);

    // Two-level screen over this thread's contiguous v-chunk.
    // Exact pass condition (== RN32(|cov|/denom) > 0.95f): |cov| >= MID*denom in f64,
    // MID = 0.95f + 2^-25. Since cov = dot*0.125 (exact) and denom = RN(wsd*sstd),
    // it is implied by |dot| >= 7.5999995*wsd*sstd, so the f32 screen
    // |dot| >= wsd*(sstd*7.5999f) (worst case <= 7.59993*wsd*sstd) has NO false
    // negatives; false positives re-filtered by the exact f64 test in the rare path.
    float best = -INFINITY;
    int bi = -1;
    float m = 0.f;  // max |corr| over PASSING elements only (sufficient for merge)
    float thr = sstd * 7.5999f;
    int vbase = __builtin_amdgcn_readfirstlane(part << 7);
    const float* wp = wrec + (size_t)vbase * 16;  // uniform -> scalar loads
    const double MID = 0x1.E66667p-1;
#pragma unroll 8
    for (int i = 0; i < 128; i++) {
        float w0 = wp[i * 16 + 0], w1 = wp[i * 16 + 1], w2 = wp[i * 16 + 2], w3 = wp[i * 16 + 3];
        float w4 = wp[i * 16 + 4], w5 = wp[i * 16 + 5], w6 = wp[i * 16 + 6], w7 = wp[i * 16 + 7];
        float wsd = wp[i * 16 + 8];
        // keep EXACT summation order of previous rounds (mul + fma chain)
        float dot = segc[0] * w0 + segc[1] * w1 + segc[2] * w2 + segc[3] * w3
                  + segc[4] * w4 + segc[5] * w5 + segc[6] * w6 + segc[7] * w7;
        float rhs = wsd * thr;
        if (__builtin_expect(fabsf(dot) >= rhs, 0)) {
            float cov = dot * 0.125f;          // exact (power-of-2 scale)
            float denom = wsd * sstd;
            if ((double)fabsf(cov) >= MID * (double)denom) {
                float c = (denom == 0.f) ? 0.f : cov / denom;
                float a = fabsf(c);
                if (a > THRESH_ && best < a) { best = c; bi = vbase + i; }
                m = fmaxf(m, a);
            }
        }
    }
    stb[t] = best;
    sti[t] = bi;
    stm[t] = m;
    if (t < 128) tree[t] = sum; // sum of 8 elements of segment t
    __syncthreads();

    // build sum tree (pairwise, matching Haar cascade structure)
    if (t < 64) tree[128 + t] = tree[2 * t] + tree[2 * t + 1];
    __syncthreads();
    if (t < 32) tree[192 + t] = tree[128 + 2 * t] + tree[128 + 2 * t + 1];
    __syncthreads();
    if (t < 16) tree[224 + t] = tree[192 + 2 * t] + tree[192 + 2 * t + 1];
    __syncthreads();
    if (t < 8) tree[240 + t] = tree[224 + 2 * t] + tree[224 + 2 * t + 1];
    __syncthreads();
    if (t < 4) tree[248 + t] = tree[240 + 2 * t] + tree[240 + 2 * t + 1];
    __syncthreads();
    if (t < 2) tree[252 + t] = tree[248 + 2 * t] + tree[248 + 2 * t + 1];
    __syncthreads();

    if (t < 128) {
        // ordered merge of the 8 v-chunk states for segment s = t
        float Bb = stb[t];
        int I = sti[t];
#pragma unroll
        for (int p = 1; p < 8; p++) {
            float yb = stb[p * 128 + t];
            int yi = sti[p * 128 + t];
            float ym = stm[p * 128 + t];
            bool take = (yi != -1) && (!(Bb > THRESH_) || (ym > Bb));
            if (take) { Bb = yb; I = yi; }
        }
        float mask = (I >= 0) ? 1.f : 0.f;

        // haar coefficients: hc[l] = 2^{-k/2} * (S_{2j} - S_{2j+1}), k = 10-l
        const int base[7] = {252, 248, 240, 224, 192, 128, 0};
        const float scl[7] = {0.03125f, 0.04419417382415922f, 0.0625f,
                              0.08838834764831843f, 0.125f,
                              0.17677669529663687f, 0.25f};
        float hcv[8];
#pragma unroll
        for (int l = 0; l < 7; l++) {
            int j = (t << l) >> 7;
            hcv[l] = scl[l] * (tree[base[l] + 2 * j] - tree[base[l] + 2 * j + 1]);
        }
        float s4a = seg[0] + seg[1] + seg[2] + seg[3];
        float s4b = seg[4] + seg[5] + seg[6] + seg[7];
        hcv[7] = 0.3535533905932738f * (s4a - s4b);

        int row = b * 128 + t;
#pragma unroll
        for (int l = 0; l < 8; l++) hcw[row * 8 + l] = hcv[l] * mask;
        idxw[row] = I;
    }
}

// output assembly: out[r,:] = pos[s] + mask*(word_emb[idx] + sum_l hc[l]*haar_emb[l])
// 192-thread blocks: wave = one column-third (64 float4s), 16 rows per block.
// Each lane holds its 8-entry haar_emb column slice in 32 VGPRs.
__global__ __launch_bounds__(192) void k2_out(const float* __restrict__ word_emb,
                                              const float* __restrict__ haar_emb,
                                              const float* __restrict__ pos_emb,
                                              const float* __restrict__ hcw,
                                              const int* __restrict__ idxw,
                                              float* __restrict__ out) {
    int lane = threadIdx.x & 63;
    int third = threadIdx.x >> 6;   // 0,1,2
    int c = third * 64 + lane;      // float4 column owned by this lane

    float4 he[8];
    const float4* hg = (const float4*)haar_emb;
#pragma unroll
    for (int l = 0; l < 8; l++) he[l] = hg[l * 192 + c];

    int rbase = (int)blockIdx.x * 16;
    for (int k = 0; k < 16; k++) {
        int r = rbase + k;          // block-uniform
        int iv = idxw[r];           // uniform -> scalar load + uniform branch
        const float4* p4 = (const float4*)pos_emb + (r & 127) * 192;
        float4* o4 = (float4*)out + (size_t)r * 192;
        if (iv >= 0) {
            float h[8];
#pragma unroll
            for (int l = 0; l < 8; l++) h[l] = hcw[r * 8 + l];  // uniform -> s_load
            const float4* w4 = (const float4*)word_emb + (size_t)iv * 192;
            float4 p = p4[c];
            float4 w = w4[c];
            float4 acc;
            acc.x = p.x + w.x; acc.y = p.y + w.y;
            acc.z = p.z + w.z; acc.w = p.w + w.w;
#pragma unroll
            for (int l = 0; l < 8; l++) {
                acc.x += h[l] * he[l].x;
                acc.y += h[l] * he[l].y;
                acc.z += h[l] * he[l].z;
                acc.w += h[l] * he[l].w;
            }
            o4[c] = acc;
        } else {
            o4[c] = p4[c];
        }
    }
}

extern "C" void kernel_launch(void* const* d_in, const int* in_sizes, int n_in,
                              void* d_out, int out_size, void* d_ws, size_t ws_size,
                              hipStream_t stream) {
    const float* X        = (const float*)d_in[0];
    const float* vocab    = (const float*)d_in[1];
    const float* word_emb = (const float*)d_in[2];
    const float* haar_emb = (const float*)d_in[3];
    const float* pos_emb  = (const float*)d_in[4];
    float* out = (float*)d_out;

    float* wsf  = (float*)d_ws;
    float* wrec = wsf;
    float* hcw  = wsf + 16384;
    int*   idxw = (int*)(wsf + 16384 + 262144);

    hipLaunchKernelGGL(k0_vocab, dim3(4), dim3(256), 0, stream, vocab, wrec);
    hipLaunchKernelGGL(k1_select, dim3(256), dim3(1024), 0, stream, X, wrec, hcw, idxw);
    hipLaunchKernelGGL(k2_out, dim3(2048), dim3(192), 0, stream,
                       word_emb, haar_emb, pos_emb, hcw, idxw, out);
}

// Round 4
// 61.609 us; speedup vs baseline: 1.1823x; 1.1823x over previous
//
#include <hip/hip_runtime.h>
#include <math.h>

#define THRESH_ 0.95f

// ws layout (float units):
// [0, 8192)            wc   : centered vocab [1024][8]
// [8192, 9216)         wstd : [1024]
// [9216, 271360)       hc   : [32768][8]  (pre-masked)
// [271360, 304128)     idx  : [32768] (int)

__global__ __launch_bounds__(256) void k0_vocab(const float* __restrict__ vocab,
                                                float* __restrict__ wc,
                                                float* __restrict__ wstd) {
    int v = blockIdx.x * 256 + threadIdx.x;
    if (v >= 1024) return;
    const float4* v4 = (const float4*)vocab + v * 2;
    float4 a = v4[0], b = v4[1];
    float w[8] = {a.x, a.y, a.z, a.w, b.x, b.y, b.z, b.w};
    float s = 0.f;
#pragma unroll
    for (int c = 0; c < 8; c++) s += w[c];
    float mean = s * 0.125f;
    float ss = 0.f;
    float wcv[8];
#pragma unroll
    for (int c = 0; c < 8; c++) { wcv[c] = w[c] - mean; ss += wcv[c] * wcv[c]; }
    float sd = sqrtf(ss * 0.125f);
    float4 o0 = {wcv[0], wcv[1], wcv[2], wcv[3]};
    float4 o1 = {wcv[4], wcv[5], wcv[6], wcv[7]};
    ((float4*)wc)[v * 2] = o0;
    ((float4*)wc)[v * 2 + 1] = o1;
    wstd[v] = sd;
}

// one block per batch row b; 1024 threads: t = part*128 + s  (part = v-chunk)
__global__ __launch_bounds__(1024) void k1_select(const float* __restrict__ X,
                                                  const float* __restrict__ wc,
                                                  const float* __restrict__ wstd,
                                                  float* __restrict__ hcw,
                                                  int* __restrict__ idxw) {
    __shared__ float xrow[1024];
    __shared__ float stb[1024];
    __shared__ int   sti[1024];
    __shared__ float stm[1024];
    __shared__ float tree[254]; // sum8[128] | sum16[64]@128 | sum32[32]@192 | sum64[16]@224 | sum128[8]@240 | sum256[4]@248 | sum512[2]@252

    int t = threadIdx.x;
    int b = blockIdx.x;
    int part = t >> 7;
    int s = t & 127;

    xrow[t] = X[b * 1024 + t];
    __syncthreads();

    // segment stats (each of the 8 part-threads for segment s redundantly computes)
    float seg[8];
#pragma unroll
    for (int c = 0; c < 8; c++) seg[c] = xrow[s * 8 + c];
    float sum = 0.f;
#pragma unroll
    for (int c = 0; c < 8; c++) sum += seg[c];
    float mean = sum * 0.125f;
    float segc[8];
    float ss = 0.f;
#pragma unroll
    for (int c = 0; c < 8; c++) { segc[c] = seg[c] - mean; ss += segc[c] * segc[c]; }
    float sstd = sqrtf(ss * 0.125f);

    // Two-level screen over this thread's contiguous v-chunk.
    // Exact pass condition (== RN32(|cov|/denom) > 0.95f): |cov| >= MID*denom in f64,
    // MID = 0.95f + 2^-25. cov = dot*0.125 (exact), so it is implied by
    // |dot| >= 7.6000000238*denom. The f32 screen |dot| >= wsd*(sstd*7.5999f)
    // (worst case <= 7.59991*wsd*sstd) has NO false negatives; false positives
    // are re-filtered by the exact f64 test in the rare path.
    float best = -INFINITY;
    int bi = -1;
    float m = 0.f;  // max |corr| over PASSING elements only (sufficient for merge)
    const float4* wc4 = (const float4*)wc;
    int vbase = __builtin_amdgcn_readfirstlane(part << 7);
    const double MID = 0x1.E66667p-1;
    float thr = sstd * 7.5999f;
#pragma unroll 4
    for (int i = 0; i < 128; i++) {
        int vu = vbase + i;  // wave-uniform -> scalar loads
        float4 wa = wc4[vu * 2];
        float4 wb = wc4[vu * 2 + 1];
        float wsd = wstd[vu];
        // keep EXACT summation order of previous rounds (mul + fma chain)
        float dot = segc[0] * wa.x + segc[1] * wa.y + segc[2] * wa.z + segc[3] * wa.w
                  + segc[4] * wb.x + segc[5] * wb.y + segc[6] * wb.z + segc[7] * wb.w;
        if (__builtin_expect(fabsf(dot) >= wsd * thr, 0)) {
            float cov = dot * 0.125f;          // exact (power-of-2 scale)
            float denom = wsd * sstd;
            if ((double)fabsf(cov) >= MID * (double)denom) {
                float c = (denom == 0.f) ? 0.f : cov / denom;
                float a = fabsf(c);
                if (a > THRESH_ && best < a) { best = c; bi = vu; }
                m = fmaxf(m, a);
            }
        }
    }
    stb[t] = best;
    sti[t] = bi;
    stm[t] = m;
    if (t < 128) tree[t] = sum; // sum of 8 elements of segment t
    __syncthreads();

    // build sum tree (pairwise, matching Haar cascade structure)
    if (t < 64) tree[128 + t] = tree[2 * t] + tree[2 * t + 1];
    __syncthreads();
    if (t < 32) tree[192 + t] = tree[128 + 2 * t] + tree[128 + 2 * t + 1];
    __syncthreads();
    if (t < 16) tree[224 + t] = tree[192 + 2 * t] + tree[192 + 2 * t + 1];
    __syncthreads();
    if (t < 8) tree[240 + t] = tree[224 + 2 * t] + tree[224 + 2 * t + 1];
    __syncthreads();
    if (t < 4) tree[248 + t] = tree[240 + 2 * t] + tree[240 + 2 * t + 1];
    __syncthreads();
    if (t < 2) tree[252 + t] = tree[248 + 2 * t] + tree[248 + 2 * t + 1];
    __syncthreads();

    if (t < 128) {
        // ordered merge of the 8 v-chunk states for segment s = t
        float Bb = stb[t];
        int I = sti[t];
#pragma unroll
        for (int p = 1; p < 8; p++) {
            float yb = stb[p * 128 + t];
            int yi = sti[p * 128 + t];
            float ym = stm[p * 128 + t];
            bool take = (yi != -1) && (!(Bb > THRESH_) || (ym > Bb));
            if (take) { Bb = yb; I = yi; }
        }
        float mask = (I >= 0) ? 1.f : 0.f;

        // haar coefficients: hc[l] = 2^{-k/2} * (S_{2j} - S_{2j+1}), k = 10-l
        const int base[7] = {252, 248, 240, 224, 192, 128, 0};
        const float scl[7] = {0.03125f, 0.04419417382415922f, 0.0625f,
                              0.08838834764831843f, 0.125f,
                              0.17677669529663687f, 0.25f};
        float hcv[8];
#pragma unroll
        for (int l = 0; l < 7; l++) {
            int j = (t << l) >> 7;
            hcv[l] = scl[l] * (tree[base[l] + 2 * j] - tree[base[l] + 2 * j + 1]);
        }
        float s4a = seg[0] + seg[1] + seg[2] + seg[3];
        float s4b = seg[4] + seg[5] + seg[6] + seg[7];
        hcv[7] = 0.3535533905932738f * (s4a - s4b);

        int row = b * 128 + t;
#pragma unroll
        for (int l = 0; l < 8; l++) hcw[row * 8 + l] = hcv[l] * mask;
        idxw[row] = I;
    }
}

// output assembly: out[r,:] = pos[s] + mask*(word_emb[idx] + sum_l hc[l]*haar_emb[l])
// haar_emb slice lives in 96 VGPRs per thread (no LDS). 32 rows per block.
__global__ __launch_bounds__(256) void k2_out(const float* __restrict__ word_emb,
                                              const float* __restrict__ haar_emb,
                                              const float* __restrict__ pos_emb,
                                              const float* __restrict__ hcw,
                                              const int* __restrict__ idxw,
                                              float* __restrict__ out) {
    int t = threadIdx.x;
    int lane = t & 63, wave = t >> 6;

    // each lane owns float4-columns {lane, lane+64, lane+128}; preload its
    // 3x8 slice of haar_emb into registers (static indexing only)
    float4 he_r[3][8];
    const float4* hg = (const float4*)haar_emb;
#pragma unroll
    for (int cb = 0; cb < 3; cb++)
#pragma unroll
        for (int l = 0; l < 8; l++)
            he_r[cb][l] = hg[l * 192 + cb * 64 + lane];

    int rbase = (int)blockIdx.x * 32 + wave * 8;
    for (int k = 0; k < 8; k++) {
        int r = rbase + k;          // wave-uniform
        int iv = idxw[r];           // uniform -> scalar load + scalar branch
        int s = r & 127;
        const float4* p4 = (const float4*)pos_emb + s * 192;
        float4* o4 = (float4*)out + (size_t)r * 192;
        if (iv >= 0) {
            float h[8];
#pragma unroll
            for (int l = 0; l < 8; l++) h[l] = hcw[r * 8 + l];  // uniform -> s_load
            const float4* w4 = (const float4*)word_emb + iv * 192;
#pragma unroll
            for (int cb = 0; cb < 3; cb++) {
                int c = cb * 64 + lane;
                float4 p = p4[c];
                float4 w = w4[c];
                float4 acc;
                acc.x = p.x + w.x; acc.y = p.y + w.y;
                acc.z = p.z + w.z; acc.w = p.w + w.w;
#pragma unroll
                for (int l = 0; l < 8; l++) {
                    acc.x += h[l] * he_r[cb][l].x;
                    acc.y += h[l] * he_r[cb][l].y;
                    acc.z += h[l] * he_r[cb][l].z;
                    acc.w += h[l] * he_r[cb][l].w;
                }
                o4[c] = acc;
            }
        } else {
#pragma unroll
            for (int cb = 0; cb < 3; cb++) {
                int c = cb * 64 + lane;
                o4[c] = p4[c];
            }
        }
    }
}

extern "C" void kernel_launch(void* const* d_in, const int* in_sizes, int n_in,
                              void* d_out, int out_size, void* d_ws, size_t ws_size,
                              hipStream_t stream) {
    const float* X        = (const float*)d_in[0];
    const float* vocab    = (const float*)d_in[1];
    const float* word_emb = (const float*)d_in[2];
    const float* haar_emb = (const float*)d_in[3];
    const float* pos_emb  = (const float*)d_in[4];
    float* out = (float*)d_out;

    float* wsf  = (float*)d_ws;
    float* wc   = wsf;
    float* wstd = wsf + 8192;
    float* hcw  = wsf + 9216;
    int*   idxw = (int*)(wsf + 9216 + 262144);

    hipLaunchKernelGGL(k0_vocab, dim3(4), dim3(256), 0, stream, vocab, wc, wstd);
    hipLaunchKernelGGL(k1_select, dim3(256), dim3(1024), 0, stream, X, wc, wstd, hcw, idxw);
    hipLaunchKernelGGL(k2_out, dim3(1024), dim3(256), 0, stream,
                       word_emb, haar_emb, pos_emb, hcw, idxw, out);
}

// Round 5
// 55.344 us; speedup vs baseline: 1.3161x; 1.1132x over previous
//
#include <hip/hip_runtime.h>
#include <math.h>

#define THRESH_ 0.95f

// ws layout (float units):
// [0, 8192)            wc   : centered vocab [1024][8]
// [8192, 9216)         wstd : [1024]

__global__ __launch_bounds__(256) void k0_vocab(const float* __restrict__ vocab,
                                                float* __restrict__ wc,
                                                float* __restrict__ wstd) {
    int v = blockIdx.x * 256 + threadIdx.x;
    if (v >= 1024) return;
    const float4* v4 = (const float4*)vocab + v * 2;
    float4 a = v4[0], b = v4[1];
    float w[8] = {a.x, a.y, a.z, a.w, b.x, b.y, b.z, b.w};
    float s = 0.f;
#pragma unroll
    for (int c = 0; c < 8; c++) s += w[c];
    float mean = s * 0.125f;
    float ss = 0.f;
    float wcv[8];
#pragma unroll
    for (int c = 0; c < 8; c++) { wcv[c] = w[c] - mean; ss += wcv[c] * wcv[c]; }
    float sd = sqrtf(ss * 0.125f);
    float4 o0 = {wcv[0], wcv[1], wcv[2], wcv[3]};
    float4 o1 = {wcv[4], wcv[5], wcv[6], wcv[7]};
    ((float4*)wc)[v * 2] = o0;
    ((float4*)wc)[v * 2 + 1] = o1;
    wstd[v] = sd;
}

// Fused select + haar + output assembly. One block per batch row b.
// Phase 1: 1024 threads, t = part*128 + s  (part = v-chunk)  — identical to R4 k1.
// Phase 2: waves 0..11 assemble this block's 128 output rows from LDS state.
__global__ __launch_bounds__(1024) void k12_fused(const float* __restrict__ X,
                                                  const float* __restrict__ wc,
                                                  const float* __restrict__ wstd,
                                                  const float* __restrict__ word_emb,
                                                  const float* __restrict__ haar_emb,
                                                  const float* __restrict__ pos_emb,
                                                  float* __restrict__ out) {
    __shared__ float xrow[1024];
    __shared__ float stb[1024];
    __shared__ int   sti[1024];
    __shared__ float stm[1024];
    __shared__ float tree[254]; // sum8[128] | sum16[64]@128 | sum32[32]@192 | sum64[16]@224 | sum128[8]@240 | sum256[4]@248 | sum512[2]@252
    __shared__ float hc_lds[1024];  // [128][8]
    __shared__ int   idx_lds[128];

    int t = threadIdx.x;
    int b = blockIdx.x;
    int part = t >> 7;
    int s = t & 127;

    xrow[t] = X[b * 1024 + t];
    __syncthreads();

    // segment stats (each of the 8 part-threads for segment s redundantly computes)
    float seg[8];
#pragma unroll
    for (int c = 0; c < 8; c++) seg[c] = xrow[s * 8 + c];
    float sum = 0.f;
#pragma unroll
    for (int c = 0; c < 8; c++) sum += seg[c];
    float mean = sum * 0.125f;
    float segc[8];
    float ss = 0.f;
#pragma unroll
    for (int c = 0; c < 8; c++) { segc[c] = seg[c] - mean; ss += segc[c] * segc[c]; }
    float sstd = sqrtf(ss * 0.125f);

    // Two-level screen over this thread's contiguous v-chunk.
    // Exact pass condition (== RN32(|cov|/denom) > 0.95f): |cov| >= MID*denom in f64,
    // MID = 0.95f + 2^-25. cov = dot*0.125 (exact), so it is implied by
    // |dot| >= 7.6000000238*denom. The f32 screen |dot| >= wsd*(sstd*7.5999f)
    // (worst case <= 7.59991*wsd*sstd) has NO false negatives; false positives
    // are re-filtered by the exact f64 test in the rare path.
    float best = -INFINITY;
    int bi = -1;
    float m = 0.f;  // max |corr| over PASSING elements only (sufficient for merge)
    const float4* wc4 = (const float4*)wc;
    int vbase = __builtin_amdgcn_readfirstlane(part << 7);
    const double MID = 0x1.E66667p-1;
    float thr = sstd * 7.5999f;
#pragma unroll 4
    for (int i = 0; i < 128; i++) {
        int vu = vbase + i;  // wave-uniform -> scalar loads
        float4 wa = wc4[vu * 2];
        float4 wb = wc4[vu * 2 + 1];
        float wsd = wstd[vu];
        // keep EXACT summation order of previous rounds (mul + fma chain)
        float dot = segc[0] * wa.x + segc[1] * wa.y + segc[2] * wa.z + segc[3] * wa.w
                  + segc[4] * wb.x + segc[5] * wb.y + segc[6] * wb.z + segc[7] * wb.w;
        if (__builtin_expect(fabsf(dot) >= wsd * thr, 0)) {
            float cov = dot * 0.125f;          // exact (power-of-2 scale)
            float denom = wsd * sstd;
            if ((double)fabsf(cov) >= MID * (double)denom) {
                float c = (denom == 0.f) ? 0.f : cov / denom;
                float a = fabsf(c);
                if (a > THRESH_ && best < a) { best = c; bi = vu; }
                m = fmaxf(m, a);
            }
        }
    }
    stb[t] = best;
    sti[t] = bi;
    stm[t] = m;
    if (t < 128) tree[t] = sum; // sum of 8 elements of segment t
    __syncthreads();

    // build sum tree (pairwise, matching Haar cascade structure)
    if (t < 64) tree[128 + t] = tree[2 * t] + tree[2 * t + 1];
    __syncthreads();
    if (t < 32) tree[192 + t] = tree[128 + 2 * t] + tree[128 + 2 * t + 1];
    __syncthreads();
    if (t < 16) tree[224 + t] = tree[192 + 2 * t] + tree[192 + 2 * t + 1];
    __syncthreads();
    if (t < 8) tree[240 + t] = tree[224 + 2 * t] + tree[224 + 2 * t + 1];
    __syncthreads();
    if (t < 4) tree[248 + t] = tree[240 + 2 * t] + tree[240 + 2 * t + 1];
    __syncthreads();
    if (t < 2) tree[252 + t] = tree[248 + 2 * t] + tree[248 + 2 * t + 1];
    __syncthreads();

    if (t < 128) {
        // ordered merge of the 8 v-chunk states for segment s = t
        float Bb = stb[t];
        int I = sti[t];
#pragma unroll
        for (int p = 1; p < 8; p++) {
            float yb = stb[p * 128 + t];
            int yi = sti[p * 128 + t];
            float ym = stm[p * 128 + t];
            bool take = (yi != -1) && (!(Bb > THRESH_) || (ym > Bb));
            if (take) { Bb = yb; I = yi; }
        }
        float mask = (I >= 0) ? 1.f : 0.f;

        // haar coefficients: hc[l] = 2^{-k/2} * (S_{2j} - S_{2j+1}), k = 10-l
        const int base[7] = {252, 248, 240, 224, 192, 128, 0};
        const float scl[7] = {0.03125f, 0.04419417382415922f, 0.0625f,
                              0.08838834764831843f, 0.125f,
                              0.17677669529663687f, 0.25f};
        float hcv[8];
#pragma unroll
        for (int l = 0; l < 7; l++) {
            int j = (t << l) >> 7;
            hcv[l] = scl[l] * (tree[base[l] + 2 * j] - tree[base[l] + 2 * j + 1]);
        }
        float s4a = seg[0] + seg[1] + seg[2] + seg[3];
        float s4b = seg[4] + seg[5] + seg[6] + seg[7];
        hcv[7] = 0.3535533905932738f * (s4a - s4b);

#pragma unroll
        for (int l = 0; l < 8; l++) hc_lds[t * 8 + l] = hcv[l] * mask;
        idx_lds[t] = I;
    }
    __syncthreads();

    // ---- phase 2: output assembly for this block's 128 rows ----
    // waves 0..11: third = w%3 (64 float4 columns), row group = w/3 (32 rows).
    int w = t >> 6;
    int lane = t & 63;
    if (w < 12) {
        int third = w % 3;
        int grp = w / 3;
        int c = third * 64 + lane;   // float4 column owned by this lane

        float4 he[8];
        const float4* hg = (const float4*)haar_emb;
#pragma unroll
        for (int l = 0; l < 8; l++) he[l] = hg[l * 192 + c];

        const float4* pos4 = (const float4*)pos_emb;
        float4* out4 = (float4*)out + (size_t)b * 128 * 192;

#pragma unroll 2
        for (int k = 0; k < 32; k++) {
            int row = grp * 32 + k;
            int iv = idx_lds[row];
            float4 p = pos4[row * 192 + c];
            float4* o4 = out4 + row * 192;
            if (iv >= 0) {
                float h[8];
#pragma unroll
                for (int l = 0; l < 8; l++) h[l] = hc_lds[row * 8 + l];
                const float4* w4 = (const float4*)word_emb + (size_t)iv * 192;
                float4 wv = w4[c];
                float4 acc;
                acc.x = p.x + wv.x; acc.y = p.y + wv.y;
                acc.z = p.z + wv.z; acc.w = p.w + wv.w;
#pragma unroll
                for (int l = 0; l < 8; l++) {
                    acc.x += h[l] * he[l].x;
                    acc.y += h[l] * he[l].y;
                    acc.z += h[l] * he[l].z;
                    acc.w += h[l] * he[l].w;
                }
                o4[c] = acc;
            } else {
                o4[c] = p;
            }
        }
    }
}

extern "C" void kernel_launch(void* const* d_in, const int* in_sizes, int n_in,
                              void* d_out, int out_size, void* d_ws, size_t ws_size,
                              hipStream_t stream) {
    const float* X        = (const float*)d_in[0];
    const float* vocab    = (const float*)d_in[1];
    const float* word_emb = (const float*)d_in[2];
    const float* haar_emb = (const float*)d_in[3];
    const float* pos_emb  = (const float*)d_in[4];
    float* out = (float*)d_out;

    float* wsf  = (float*)d_ws;
    float* wc   = wsf;
    float* wstd = wsf + 8192;

    hipLaunchKernelGGL(k0_vocab, dim3(4), dim3(256), 0, stream, vocab, wc, wstd);
    hipLaunchKernelGGL(k12_fused, dim3(256), dim3(1024), 0, stream,
                       X, wc, wstd, word_emb, haar_emb, pos_emb, out);
}

// Round 7
// 54.377 us; speedup vs baseline: 1.3395x; 1.0178x over previous
//
#include <hip/hip_runtime.h>
#include <math.h>

#define THRESH_ 0.95f

typedef float nfloat4 __attribute__((ext_vector_type(4)));

// ws layout (float units):
// [0, 8192)            wc   : centered vocab [1024][8]
// [8192, 9216)         wstd : [1024]

__global__ __launch_bounds__(256) void k0_vocab(const float* __restrict__ vocab,
                                                float* __restrict__ wc,
                                                float* __restrict__ wstd) {
    int v = blockIdx.x * 256 + threadIdx.x;
    if (v >= 1024) return;
    const float4* v4 = (const float4*)vocab + v * 2;
    float4 a = v4[0], b = v4[1];
    float w[8] = {a.x, a.y, a.z, a.w, b.x, b.y, b.z, b.w};
    float s = 0.f;
#pragma unroll
    for (int c = 0; c < 8; c++) s += w[c];
    float mean = s * 0.125f;
    float ss = 0.f;
    float wcv[8];
#pragma unroll
    for (int c = 0; c < 8; c++) { wcv[c] = w[c] - mean; ss += wcv[c] * wcv[c]; }
    float sd = sqrtf(ss * 0.125f);
    float4 o0 = {wcv[0], wcv[1], wcv[2], wcv[3]};
    float4 o1 = {wcv[4], wcv[5], wcv[6], wcv[7]};
    ((float4*)wc)[v * 2] = o0;
    ((float4*)wc)[v * 2 + 1] = o1;
    wstd[v] = sd;
}

// Fused select + haar + output assembly. One block per batch row b.
// Phase 1: 1024 threads, t = part*128 + s  (part = v-chunk)  — identical to R5.
// Phase 2: waves 0..11, branchless 2-row software pipeline, NT stores.
__global__ __launch_bounds__(1024) void k12_fused(const float* __restrict__ X,
                                                  const float* __restrict__ wc,
                                                  const float* __restrict__ wstd,
                                                  const float* __restrict__ word_emb,
                                                  const float* __restrict__ haar_emb,
                                                  const float* __restrict__ pos_emb,
                                                  float* __restrict__ out) {
    __shared__ float xrow[1024];
    __shared__ float stb[1024];
    __shared__ int   sti[1024];
    __shared__ float stm[1024];
    __shared__ float tree[254]; // sum8[128] | sum16[64]@128 | sum32[32]@192 | sum64[16]@224 | sum128[8]@240 | sum256[4]@248 | sum512[2]@252
    __shared__ float hc_lds[1024];  // [128][8]
    __shared__ int   idx_lds[128];

    int t = threadIdx.x;
    int b = blockIdx.x;
    int part = t >> 7;
    int s = t & 127;

    xrow[t] = X[b * 1024 + t];
    __syncthreads();

    // segment stats (each of the 8 part-threads for segment s redundantly computes)
    float seg[8];
#pragma unroll
    for (int c = 0; c < 8; c++) seg[c] = xrow[s * 8 + c];
    float sum = 0.f;
#pragma unroll
    for (int c = 0; c < 8; c++) sum += seg[c];
    float mean = sum * 0.125f;
    float segc[8];
    float ss = 0.f;
#pragma unroll
    for (int c = 0; c < 8; c++) { segc[c] = seg[c] - mean; ss += segc[c] * segc[c]; }
    float sstd = sqrtf(ss * 0.125f);

    // Two-level screen over this thread's contiguous v-chunk.
    // Exact pass condition (== RN32(|cov|/denom) > 0.95f): |cov| >= MID*denom in f64,
    // MID = 0.95f + 2^-25. cov = dot*0.125 (exact), so it is implied by
    // |dot| >= 7.6000000238*denom. The f32 screen |dot| >= wsd*(sstd*7.5999f)
    // (worst case <= 7.59991*wsd*sstd) has NO false negatives; false positives
    // are re-filtered by the exact f64 test in the rare path.
    float best = -INFINITY;
    int bi = -1;
    float m = 0.f;  // max |corr| over PASSING elements only (sufficient for merge)
    const float4* wc4 = (const float4*)wc;
    int vbase = __builtin_amdgcn_readfirstlane(part << 7);
    const double MID = 0x1.E66667p-1;
    float thr = sstd * 7.5999f;
#pragma unroll 4
    for (int i = 0; i < 128; i++) {
        int vu = vbase + i;  // wave-uniform -> scalar loads
        float4 wa = wc4[vu * 2];
        float4 wb = wc4[vu * 2 + 1];
        float wsd = wstd[vu];
        // keep EXACT summation order of previous rounds (mul + fma chain)
        float dot = segc[0] * wa.x + segc[1] * wa.y + segc[2] * wa.z + segc[3] * wa.w
                  + segc[4] * wb.x + segc[5] * wb.y + segc[6] * wb.z + segc[7] * wb.w;
        if (__builtin_expect(fabsf(dot) >= wsd * thr, 0)) {
            float cov = dot * 0.125f;          // exact (power-of-2 scale)
            float denom = wsd * sstd;
            if ((double)fabsf(cov) >= MID * (double)denom) {
                float c = (denom == 0.f) ? 0.f : cov / denom;
                float a = fabsf(c);
                if (a > THRESH_ && best < a) { best = c; bi = vu; }
                m = fmaxf(m, a);
            }
        }
    }
    stb[t] = best;
    sti[t] = bi;
    stm[t] = m;
    if (t < 128) tree[t] = sum; // sum of 8 elements of segment t
    __syncthreads();

    // build sum tree (pairwise, matching Haar cascade structure)
    if (t < 64) tree[128 + t] = tree[2 * t] + tree[2 * t + 1];
    __syncthreads();
    if (t < 32) tree[192 + t] = tree[128 + 2 * t] + tree[128 + 2 * t + 1];
    __syncthreads();
    if (t < 16) tree[224 + t] = tree[192 + 2 * t] + tree[192 + 2 * t + 1];
    __syncthreads();
    if (t < 8) tree[240 + t] = tree[224 + 2 * t] + tree[224 + 2 * t + 1];
    __syncthreads();
    if (t < 4) tree[248 + t] = tree[240 + 2 * t] + tree[240 + 2 * t + 1];
    __syncthreads();
    if (t < 2) tree[252 + t] = tree[248 + 2 * t] + tree[248 + 2 * t + 1];
    __syncthreads();

    if (t < 128) {
        // ordered merge of the 8 v-chunk states for segment s = t
        float Bb = stb[t];
        int I = sti[t];
#pragma unroll
        for (int p = 1; p < 8; p++) {
            float yb = stb[p * 128 + t];
            int yi = sti[p * 128 + t];
            float ym = stm[p * 128 + t];
            bool take = (yi != -1) && (!(Bb > THRESH_) || (ym > Bb));
            if (take) { Bb = yb; I = yi; }
        }
        float mask = (I >= 0) ? 1.f : 0.f;

        // haar coefficients: hc[l] = 2^{-k/2} * (S_{2j} - S_{2j+1}), k = 10-l
        const int base[7] = {252, 248, 240, 224, 192, 128, 0};
        const float scl[7] = {0.03125f, 0.04419417382415922f, 0.0625f,
                              0.08838834764831843f, 0.125f,
                              0.17677669529663687f, 0.25f};
        float hcv[8];
#pragma unroll
        for (int l = 0; l < 7; l++) {
            int j = (t << l) >> 7;
            hcv[l] = scl[l] * (tree[base[l] + 2 * j] - tree[base[l] + 2 * j + 1]);
        }
        float s4a = seg[0] + seg[1] + seg[2] + seg[3];
        float s4b = seg[4] + seg[5] + seg[6] + seg[7];
        hcv[7] = 0.3535533905932738f * (s4a - s4b);

#pragma unroll
        for (int l = 0; l < 8; l++) hc_lds[t * 8 + l] = hcv[l] * mask;
        idx_lds[t] = I;
    }
    __syncthreads();

    // ---- phase 2: output assembly for this block's 128 rows ----
    // waves 0..11: third = w%3 (64 float4 columns), row group = w/3 (32 rows).
    // Branchless + 2-row pipeline: hc is pre-masked, word term via fma(wv,msk,p).
    int w = t >> 6;
    int lane = t & 63;
    if (w < 12) {
        int third = w % 3;
        int grp = w / 3;
        int c = third * 64 + lane;   // float4 column owned by this lane

        float4 he[8];
        const float4* hg = (const float4*)haar_emb;
#pragma unroll
        for (int l = 0; l < 8; l++) he[l] = hg[l * 192 + c];

        const float4* pos4 = (const float4*)pos_emb;
        const float4* we4 = (const float4*)word_emb;
        float4* out4 = (float4*)out + (size_t)b * 128 * 192;

        for (int k = 0; k < 32; k += 2) {
            int row0 = grp * 32 + k;
            int row1 = row0 + 1;
            int iv0 = idx_lds[row0];
            int iv1 = idx_lds[row1];
            int ivc0 = iv0 < 0 ? 0 : iv0;
            int ivc1 = iv1 < 0 ? 0 : iv1;
            float msk0 = iv0 < 0 ? 0.f : 1.f;
            float msk1 = iv1 < 0 ? 0.f : 1.f;
            // issue both rows' loads before either compute
            float4 p0 = pos4[row0 * 192 + c];
            float4 w0 = we4[(size_t)ivc0 * 192 + c];
            float4 h0a = *(const float4*)&hc_lds[row0 * 8];
            float4 h0b = *(const float4*)&hc_lds[row0 * 8 + 4];
            float4 p1 = pos4[row1 * 192 + c];
            float4 w1 = we4[(size_t)ivc1 * 192 + c];
            float4 h1a = *(const float4*)&hc_lds[row1 * 8];
            float4 h1b = *(const float4*)&hc_lds[row1 * 8 + 4];

            float4 acc0;
            acc0.x = fmaf(w0.x, msk0, p0.x);
            acc0.y = fmaf(w0.y, msk0, p0.y);
            acc0.z = fmaf(w0.z, msk0, p0.z);
            acc0.w = fmaf(w0.w, msk0, p0.w);
            float h0[8] = {h0a.x, h0a.y, h0a.z, h0a.w, h0b.x, h0b.y, h0b.z, h0b.w};
#pragma unroll
            for (int l = 0; l < 8; l++) {
                acc0.x += h0[l] * he[l].x;
                acc0.y += h0[l] * he[l].y;
                acc0.z += h0[l] * he[l].z;
                acc0.w += h0[l] * he[l].w;
            }
            {
                nfloat4 nv = {acc0.x, acc0.y, acc0.z, acc0.w};
                __builtin_nontemporal_store(nv, (nfloat4*)&out4[row0 * 192 + c]);
            }

            float4 acc1;
            acc1.x = fmaf(w1.x, msk1, p1.x);
            acc1.y = fmaf(w1.y, msk1, p1.y);
            acc1.z = fmaf(w1.z, msk1, p1.z);
            acc1.w = fmaf(w1.w, msk1, p1.w);
            float h1[8] = {h1a.x, h1a.y, h1a.z, h1a.w, h1b.x, h1b.y, h1b.z, h1b.w};
#pragma unroll
            for (int l = 0; l < 8; l++) {
                acc1.x += h1[l] * he[l].x;
                acc1.y += h1[l] * he[l].y;
                acc1.z += h1[l] * he[l].z;
                acc1.w += h1[l] * he[l].w;
            }
            {
                nfloat4 nv = {acc1.x, acc1.y, acc1.z, acc1.w};
                __builtin_nontemporal_store(nv, (nfloat4*)&out4[row1 * 192 + c]);
            }
        }
    }
}

extern "C" void kernel_launch(void* const* d_in, const int* in_sizes, int n_in,
                              void* d_out, int out_size, void* d_ws, size_t ws_size,
                              hipStream_t stream) {
    const float* X        = (const float*)d_in[0];
    const float* vocab    = (const float*)d_in[1];
    const float* word_emb = (const float*)d_in[2];
    const float* haar_emb = (const float*)d_in[3];
    const float* pos_emb  = (const float*)d_in[4];
    float* out = (float*)d_out;

    float* wsf  = (float*)d_ws;
    float* wc   = wsf;
    float* wstd = wsf + 8192;

    hipLaunchKernelGGL(k0_vocab, dim3(4), dim3(256), 0, stream, vocab, wc, wstd);
    hipLaunchKernelGGL(k12_fused, dim3(256), dim3(1024), 0, stream,
                       X, wc, wstd, word_emb, haar_emb, pos_emb, out);
}

// Round 8
// 48.318 us; speedup vs baseline: 1.5075x; 1.1254x over previous
//
#include <hip/hip_runtime.h>
#include <math.h>

#define THRESH_ 0.95f

typedef float nfloat4 __attribute__((ext_vector_type(4)));

// ws layout (float units):
// [0, 8192)            wc   : centered vocab [1024][8]
// [8192, 9216)         wstd : [1024]

__global__ __launch_bounds__(256) void k0_vocab(const float* __restrict__ vocab,
                                                float* __restrict__ wc,
                                                float* __restrict__ wstd) {
    int v = blockIdx.x * 256 + threadIdx.x;
    if (v >= 1024) return;
    const float4* v4 = (const float4*)vocab + v * 2;
    float4 a = v4[0], b = v4[1];
    float w[8] = {a.x, a.y, a.z, a.w, b.x, b.y, b.z, b.w};
    float s = 0.f;
#pragma unroll
    for (int c = 0; c < 8; c++) s += w[c];
    float mean = s * 0.125f;
    float ss = 0.f;
    float wcv[8];
#pragma unroll
    for (int c = 0; c < 8; c++) { wcv[c] = w[c] - mean; ss += wcv[c] * wcv[c]; }
    float sd = sqrtf(ss * 0.125f);
    float4 o0 = {wcv[0], wcv[1], wcv[2], wcv[3]};
    float4 o1 = {wcv[4], wcv[5], wcv[6], wcv[7]};
    ((float4*)wc)[v * 2] = o0;
    ((float4*)wc)[v * 2 + 1] = o1;
    wstd[v] = sd;
}

// Fused select + haar + output assembly. One block per batch row b.
// Phase 1: 1024 threads, t = part*128 + s; vocab table staged in LDS
//          (36 KB) so inner-loop reads are LDS broadcasts, not L2 streams.
// Phase 2: waves 0..11, branchless 2-row software pipeline, NT stores.
__global__ __launch_bounds__(1024) void k12_fused(const float* __restrict__ X,
                                                  const float* __restrict__ wc,
                                                  const float* __restrict__ wstd,
                                                  const float* __restrict__ word_emb,
                                                  const float* __restrict__ haar_emb,
                                                  const float* __restrict__ pos_emb,
                                                  float* __restrict__ out) {
    __shared__ float4 wcl4[2048];   // centered vocab [1024][8] as float4 pairs (32 KB)
    __shared__ float  wsl[1024];    // word stds (4 KB)
    __shared__ float xrow[1024];
    __shared__ float stb[1024];
    __shared__ int   sti[1024];
    __shared__ float stm[1024];
    __shared__ float tree[254]; // sum8[128] | sum16[64]@128 | sum32[32]@192 | sum64[16]@224 | sum128[8]@240 | sum256[4]@248 | sum512[2]@252
    __shared__ float hc_lds[1024];  // [128][8]
    __shared__ int   idx_lds[128];

    int t = threadIdx.x;
    int b = blockIdx.x;
    int part = t >> 7;
    int s = t & 127;

    // stage X row + vocab table into LDS
    xrow[t] = X[b * 1024 + t];
    {
        const float4* wcg = (const float4*)wc;
        wcl4[t] = wcg[t];
        wcl4[t + 1024] = wcg[t + 1024];
        wsl[t] = wstd[t];
    }
    __syncthreads();

    // segment stats (each of the 8 part-threads for segment s redundantly computes)
    float seg[8];
#pragma unroll
    for (int c = 0; c < 8; c++) seg[c] = xrow[s * 8 + c];
    float sum = 0.f;
#pragma unroll
    for (int c = 0; c < 8; c++) sum += seg[c];
    float mean = sum * 0.125f;
    float segc[8];
    float ss = 0.f;
#pragma unroll
    for (int c = 0; c < 8; c++) { segc[c] = seg[c] - mean; ss += segc[c] * segc[c]; }
    float sstd = sqrtf(ss * 0.125f);

    // Two-level screen over this thread's contiguous v-chunk.
    // Exact pass condition (== RN32(|cov|/denom) > 0.95f): |cov| >= MID*denom in f64,
    // MID = 0.95f + 2^-25. cov = dot*0.125 (exact), so it is implied by
    // |dot| >= 7.6000000238*denom. The f32 screen |dot| >= wsd*(sstd*7.5999f)
    // (worst case <= 7.59991*wsd*sstd) has NO false negatives; false positives
    // are re-filtered by the exact f64 test in the rare path.
    float best = -INFINITY;
    int bi = -1;
    float m = 0.f;  // max |corr| over PASSING elements only (sufficient for merge)
    int vbase = __builtin_amdgcn_readfirstlane(part << 7);
    const double MID = 0x1.E66667p-1;
    float thr = sstd * 7.5999f;
#pragma unroll 4
    for (int i = 0; i < 128; i++) {
        int vu = vbase + i;  // wave-uniform -> LDS broadcast reads
        float4 wa = wcl4[vu * 2];
        float4 wb = wcl4[vu * 2 + 1];
        float wsd = wsl[vu];
        // keep EXACT summation order of previous rounds (mul + fma chain)
        float dot = segc[0] * wa.x + segc[1] * wa.y + segc[2] * wa.z + segc[3] * wa.w
                  + segc[4] * wb.x + segc[5] * wb.y + segc[6] * wb.z + segc[7] * wb.w;
        if (__builtin_expect(fabsf(dot) >= wsd * thr, 0)) {
            float cov = dot * 0.125f;          // exact (power-of-2 scale)
            float denom = wsd * sstd;
            if ((double)fabsf(cov) >= MID * (double)denom) {
                float c = (denom == 0.f) ? 0.f : cov / denom;
                float a = fabsf(c);
                if (a > THRESH_ && best < a) { best = c; bi = vu; }
                m = fmaxf(m, a);
            }
        }
    }
    stb[t] = best;
    sti[t] = bi;
    stm[t] = m;
    if (t < 128) tree[t] = sum; // sum of 8 elements of segment t
    __syncthreads();

    // build sum tree (pairwise, matching Haar cascade structure)
    if (t < 64) tree[128 + t] = tree[2 * t] + tree[2 * t + 1];
    __syncthreads();
    if (t < 32) tree[192 + t] = tree[128 + 2 * t] + tree[128 + 2 * t + 1];
    __syncthreads();
    if (t < 16) tree[224 + t] = tree[192 + 2 * t] + tree[192 + 2 * t + 1];
    __syncthreads();
    if (t < 8) tree[240 + t] = tree[224 + 2 * t] + tree[224 + 2 * t + 1];
    __syncthreads();
    if (t < 4) tree[248 + t] = tree[240 + 2 * t] + tree[240 + 2 * t + 1];
    __syncthreads();
    if (t < 2) tree[252 + t] = tree[248 + 2 * t] + tree[248 + 2 * t + 1];
    __syncthreads();

    if (t < 128) {
        // ordered merge of the 8 v-chunk states for segment s = t
        float Bb = stb[t];
        int I = sti[t];
#pragma unroll
        for (int p = 1; p < 8; p++) {
            float yb = stb[p * 128 + t];
            int yi = sti[p * 128 + t];
            float ym = stm[p * 128 + t];
            bool take = (yi != -1) && (!(Bb > THRESH_) || (ym > Bb));
            if (take) { Bb = yb; I = yi; }
        }
        float mask = (I >= 0) ? 1.f : 0.f;

        // haar coefficients: hc[l] = 2^{-k/2} * (S_{2j} - S_{2j+1}), k = 10-l
        const int base[7] = {252, 248, 240, 224, 192, 128, 0};
        const float scl[7] = {0.03125f, 0.04419417382415922f, 0.0625f,
                              0.08838834764831843f, 0.125f,
                              0.17677669529663687f, 0.25f};
        float hcv[8];
#pragma unroll
        for (int l = 0; l < 7; l++) {
            int j = (t << l) >> 7;
            hcv[l] = scl[l] * (tree[base[l] + 2 * j] - tree[base[l] + 2 * j + 1]);
        }
        float s4a = seg[0] + seg[1] + seg[2] + seg[3];
        float s4b = seg[4] + seg[5] + seg[6] + seg[7];
        hcv[7] = 0.3535533905932738f * (s4a - s4b);

#pragma unroll
        for (int l = 0; l < 8; l++) hc_lds[t * 8 + l] = hcv[l] * mask;
        idx_lds[t] = I;
    }
    __syncthreads();

    // ---- phase 2: output assembly for this block's 128 rows ----
    // waves 0..11: third = w%3 (64 float4 columns), row group = w/3 (32 rows).
    // Branchless + 2-row pipeline: hc is pre-masked, word term via fma(wv,msk,p).
    int w = t >> 6;
    int lane = t & 63;
    if (w < 12) {
        int third = w % 3;
        int grp = w / 3;
        int c = third * 64 + lane;   // float4 column owned by this lane

        float4 he[8];
        const float4* hg = (const float4*)haar_emb;
#pragma unroll
        for (int l = 0; l < 8; l++) he[l] = hg[l * 192 + c];

        const float4* pos4 = (const float4*)pos_emb;
        const float4* we4 = (const float4*)word_emb;
        float4* out4 = (float4*)out + (size_t)b * 128 * 192;

        for (int k = 0; k < 32; k += 2) {
            int row0 = grp * 32 + k;
            int row1 = row0 + 1;
            int iv0 = idx_lds[row0];
            int iv1 = idx_lds[row1];
            int ivc0 = iv0 < 0 ? 0 : iv0;
            int ivc1 = iv1 < 0 ? 0 : iv1;
            float msk0 = iv0 < 0 ? 0.f : 1.f;
            float msk1 = iv1 < 0 ? 0.f : 1.f;
            // issue both rows' loads before either compute
            float4 p0 = pos4[row0 * 192 + c];
            float4 w0 = we4[(size_t)ivc0 * 192 + c];
            float4 h0a = *(const float4*)&hc_lds[row0 * 8];
            float4 h0b = *(const float4*)&hc_lds[row0 * 8 + 4];
            float4 p1 = pos4[row1 * 192 + c];
            float4 w1 = we4[(size_t)ivc1 * 192 + c];
            float4 h1a = *(const float4*)&hc_lds[row1 * 8];
            float4 h1b = *(const float4*)&hc_lds[row1 * 8 + 4];

            float4 acc0;
            acc0.x = fmaf(w0.x, msk0, p0.x);
            acc0.y = fmaf(w0.y, msk0, p0.y);
            acc0.z = fmaf(w0.z, msk0, p0.z);
            acc0.w = fmaf(w0.w, msk0, p0.w);
            float h0[8] = {h0a.x, h0a.y, h0a.z, h0a.w, h0b.x, h0b.y, h0b.z, h0b.w};
#pragma unroll
            for (int l = 0; l < 8; l++) {
                acc0.x += h0[l] * he[l].x;
                acc0.y += h0[l] * he[l].y;
                acc0.z += h0[l] * he[l].z;
                acc0.w += h0[l] * he[l].w;
            }
            {
                nfloat4 nv = {acc0.x, acc0.y, acc0.z, acc0.w};
                __builtin_nontemporal_store(nv, (nfloat4*)&out4[row0 * 192 + c]);
            }

            float4 acc1;
            acc1.x = fmaf(w1.x, msk1, p1.x);
            acc1.y = fmaf(w1.y, msk1, p1.y);
            acc1.z = fmaf(w1.z, msk1, p1.z);
            acc1.w = fmaf(w1.w, msk1, p1.w);
            float h1[8] = {h1a.x, h1a.y, h1a.z, h1a.w, h1b.x, h1b.y, h1b.z, h1b.w};
#pragma unroll
            for (int l = 0; l < 8; l++) {
                acc1.x += h1[l] * he[l].x;
                acc1.y += h1[l] * he[l].y;
                acc1.z += h1[l] * he[l].z;
                acc1.w += h1[l] * he[l].w;
            }
            {
                nfloat4 nv = {acc1.x, acc1.y, acc1.z, acc1.w};
                __builtin_nontemporal_store(nv, (nfloat4*)&out4[row1 * 192 + c]);
            }
        }
    }
}

extern "C" void kernel_launch(void* const* d_in, const int* in_sizes, int n_in,
                              void* d_out, int out_size, void* d_ws, size_t ws_size,
                              hipStream_t stream) {
    const float* X        = (const float*)d_in[0];
    const float* vocab    = (const float*)d_in[1];
    const float* word_emb = (const float*)d_in[2];
    const float* haar_emb = (const float*)d_in[3];
    const float* pos_emb  = (const float*)d_in[4];
    float* out = (float*)d_out;

    float* wsf  = (float*)d_ws;
    float* wc   = wsf;
    float* wstd = wsf + 8192;

    hipLaunchKernelGGL(k0_vocab, dim3(4), dim3(256), 0, stream, vocab, wc, wstd);
    hipLaunchKernelGGL(k12_fused, dim3(256), dim3(1024), 0, stream,
                       X, wc, wstd, word_emb, haar_emb, pos_emb, out);
}

// Round 9
// 40.527 us; speedup vs baseline: 1.7973x; 1.1922x over previous
//
#include <hip/hip_runtime.h>
#include <math.h>

#define THRESH_ 0.95f

typedef float nfloat4 __attribute__((ext_vector_type(4)));
typedef __attribute__((ext_vector_type(8))) short short8v;
typedef __attribute__((ext_vector_type(16))) float f32x16;

__device__ __forceinline__ unsigned short f2bf_rne(float x) {
    unsigned u = __float_as_uint(x);
    u += 0x7fffu + ((u >> 16) & 1u);
    return (unsigned short)(u >> 16);
}

// ws layout (float units):
// [0, 8192)       wc   : centered vocab fp32 [1024][8]
// [8192, 9216)    wstd : [1024]
// [9216, 13312)   wcb  : bf16 vocab [1024][8] (ushort)

__global__ __launch_bounds__(256) void k0_vocab(const float* __restrict__ vocab,
                                                float* __restrict__ wc,
                                                float* __restrict__ wstd,
                                                unsigned short* __restrict__ wcb) {
    int v = blockIdx.x * 256 + threadIdx.x;
    if (v >= 1024) return;
    const float4* v4 = (const float4*)vocab + v * 2;
    float4 a = v4[0], b = v4[1];
    float w[8] = {a.x, a.y, a.z, a.w, b.x, b.y, b.z, b.w};
    float s = 0.f;
#pragma unroll
    for (int c = 0; c < 8; c++) s += w[c];
    float mean = s * 0.125f;
    float ss = 0.f;
    float wcv[8];
#pragma unroll
    for (int c = 0; c < 8; c++) { wcv[c] = w[c] - mean; ss += wcv[c] * wcv[c]; }
    float sd = sqrtf(ss * 0.125f);
    float4 o0 = {wcv[0], wcv[1], wcv[2], wcv[3]};
    float4 o1 = {wcv[4], wcv[5], wcv[6], wcv[7]};
    ((float4*)wc)[v * 2] = o0;
    ((float4*)wc)[v * 2 + 1] = o1;
    wstd[v] = sd;
    union { uint4 q; unsigned short u[8]; } pk;
#pragma unroll
    for (int c = 0; c < 8; c++) pk.u[c] = f2bf_rne(wcv[c]);
    ((uint4*)wcb)[v] = pk.q;
}

// Fused: MFMA-screened select + haar + output assembly. One block per batch row.
// Phase 1a: stage vocab (fp32 + bf16) and X row to LDS; compute segment stats.
// Phase 1b: 16 waves = 4 seg-blocks x 4 word-groups; each wave: 8x
//           mfma_f32_32x32x16_bf16 tiles (K=16, zero-padded K=8..15).
//           Screen |acc| > 7.52*sstd*wsd (proven no false negatives vs the
//           exact RN32(|cov|/denom) > 0.95f condition); rare candidates get
//           exact fp32 dot + f64 MID test + IEEE divide, applied in v-order
//           to per-(chunk,seg) ordered-scan states in LDS.
// Phase 1c: haar tree + 4-chunk ordered merge (same proven rule).
// Phase 2:  branchless 2-row pipelined output assembly, NT stores (as R8).
__global__ __launch_bounds__(1024) void k12_fused(const float* __restrict__ X,
                                                  const float* __restrict__ wc,
                                                  const float* __restrict__ wstd,
                                                  const unsigned short* __restrict__ wcb,
                                                  const float* __restrict__ word_emb,
                                                  const float* __restrict__ haar_emb,
                                                  const float* __restrict__ pos_emb,
                                                  float* __restrict__ out) {
    __shared__ float4  wcl4[2048];    // fp32 centered vocab (32 KB)
    __shared__ short8v wcb_lds[1024]; // bf16 vocab (16 KB)
    __shared__ float   wsl[1024];     // word stds (4 KB)
    __shared__ float   xrow[1024];    // 4 KB
    __shared__ float   segf[1024];    // fp32 centered segments [128][8] (4 KB)
    __shared__ short8v segb[128];     // bf16 segments (2 KB)
    __shared__ float   sstd_l[128];
    __shared__ float   thr_l[128];    // 7.52f * sstd
    __shared__ float   stb[512];      // [4 chunks][128 segs]
    __shared__ int     sti[512];
    __shared__ float   stm[512];
    __shared__ float   tree[254];
    __shared__ float   hc_lds[1024];  // [128][8]
    __shared__ int     idx_lds[128];

    int t = threadIdx.x;
    int b = blockIdx.x;

    // ---- staging ----
    xrow[t] = X[b * 1024 + t];
    {
        const float4* wcg = (const float4*)wc;
        wcl4[t] = wcg[t];
        wcl4[t + 1024] = wcg[t + 1024];
        ((uint4*)wcb_lds)[t] = ((const uint4*)wcb)[t];
        wsl[t] = wstd[t];
    }
    if (t < 512) { stb[t] = -INFINITY; sti[t] = -1; stm[t] = 0.f; }
    __syncthreads();

    // ---- segment stats (t < 128 only) ----
    if (t < 128) {
        float seg[8];
#pragma unroll
        for (int c = 0; c < 8; c++) seg[c] = xrow[t * 8 + c];
        float sum = 0.f;
#pragma unroll
        for (int c = 0; c < 8; c++) sum += seg[c];
        float mean = sum * 0.125f;
        float segc[8];
        float ss = 0.f;
#pragma unroll
        for (int c = 0; c < 8; c++) { segc[c] = seg[c] - mean; ss += segc[c] * segc[c]; }
        float sstd = sqrtf(ss * 0.125f);
        union { short8v v; unsigned short u[8]; } pk;
#pragma unroll
        for (int c = 0; c < 8; c++) { segf[t * 8 + c] = segc[c]; pk.u[c] = f2bf_rne(segc[c]); }
        segb[t] = pk.v;
        sstd_l[t] = sstd;
        thr_l[t] = 7.52f * sstd;
        tree[t] = sum;
    }
    __syncthreads();

    // ---- MFMA screen ----
    int w = t >> 6, lane = t & 63;
    {
        int sb = w & 3;        // seg-block (32 segments)
        int g = w >> 2;        // word-group (chunk): words [g*256, g*256+256)
        int half = lane >> 5;

        short8v af = {0, 0, 0, 0, 0, 0, 0, 0};
        if (lane < 32) af = segb[sb * 32 + lane];

        float thr_r[16];
#pragma unroll
        for (int i = 0; i < 16; i++) {
            int row = (i & 3) + 8 * (i >> 2) + 4 * half;
            thr_r[i] = thr_l[sb * 32 + row];
        }

        const double MID = 0x1.E66667p-1;
        for (int j = 0; j < 8; j++) {
            int wb = g * 8 + j;
            short8v bf = {0, 0, 0, 0, 0, 0, 0, 0};
            if (lane < 32) bf = wcb_lds[wb * 32 + lane];
            float wsd_c = wsl[wb * 32 + (lane & 31)];

            f32x16 accz = {0.f, 0.f, 0.f, 0.f, 0.f, 0.f, 0.f, 0.f,
                           0.f, 0.f, 0.f, 0.f, 0.f, 0.f, 0.f, 0.f};
            f32x16 acc = __builtin_amdgcn_mfma_f32_32x32x16_bf16(af, bf, accz, 0, 0, 0);

            bool anyp = false;
#pragma unroll
            for (int i = 0; i < 16; i++) anyp |= (fabsf(acc[i]) > thr_r[i] * wsd_c);

            if (__builtin_expect(anyp, 0)) {
#pragma unroll
                for (int i = 0; i < 16; i++) {
                    unsigned long long mi = __ballot(fabsf(acc[i]) > thr_r[i] * wsd_c);
                    while (mi) {
                        int src = __builtin_ctzll(mi);
                        mi &= mi - 1;
                        if (lane == src) {
                            int col = src & 31;
                            int seg_r = sb * 32 + (i & 3) + 8 * (i >> 2) + 4 * (src >> 5);
                            int v = wb * 32 + col;
                            float sst = sstd_l[seg_r];
                            float wsd = wsl[v];
                            const float* sc = &segf[seg_r * 8];
                            float4 wa = wcl4[v * 2];
                            float4 wbv = wcl4[v * 2 + 1];
                            // EXACT mul/fma order of previous rounds
                            float dot = sc[0] * wa.x + sc[1] * wa.y + sc[2] * wa.z + sc[3] * wa.w
                                      + sc[4] * wbv.x + sc[5] * wbv.y + sc[6] * wbv.z + sc[7] * wbv.w;
                            float cov = dot * 0.125f;
                            float denom = wsd * sst;
                            if ((double)fabsf(cov) >= MID * (double)denom) {
                                float c = (denom == 0.f) ? 0.f : cov / denom;
                                float a = fabsf(c);
                                int sidx = g * 128 + seg_r;
                                stm[sidx] = fmaxf(stm[sidx], a);
                                if (a > THRESH_ && stb[sidx] < a) { stb[sidx] = c; sti[sidx] = v; }
                            }
                        }
                    }
                }
            }
        }
    }
    __syncthreads();

    // ---- haar sum tree ----
    if (t < 64) tree[128 + t] = tree[2 * t] + tree[2 * t + 1];
    __syncthreads();
    if (t < 32) tree[192 + t] = tree[128 + 2 * t] + tree[128 + 2 * t + 1];
    __syncthreads();
    if (t < 16) tree[224 + t] = tree[192 + 2 * t] + tree[192 + 2 * t + 1];
    __syncthreads();
    if (t < 8) tree[240 + t] = tree[224 + 2 * t] + tree[224 + 2 * t + 1];
    __syncthreads();
    if (t < 4) tree[248 + t] = tree[240 + 2 * t] + tree[240 + 2 * t + 1];
    __syncthreads();
    if (t < 2) tree[252 + t] = tree[248 + 2 * t] + tree[248 + 2 * t + 1];
    __syncthreads();

    // ---- ordered 4-chunk merge + haar coefficients (t < 128) ----
    if (t < 128) {
        float Bb = stb[t];
        int I = sti[t];
#pragma unroll
        for (int p = 1; p < 4; p++) {
            float yb = stb[p * 128 + t];
            int yi = sti[p * 128 + t];
            float ym = stm[p * 128 + t];
            bool take = (yi != -1) && (!(Bb > THRESH_) || (ym > Bb));
            if (take) { Bb = yb; I = yi; }
        }
        float mask = (I >= 0) ? 1.f : 0.f;

        const int base[7] = {252, 248, 240, 224, 192, 128, 0};
        const float scl[7] = {0.03125f, 0.04419417382415922f, 0.0625f,
                              0.08838834764831843f, 0.125f,
                              0.17677669529663687f, 0.25f};
        float hcv[8];
#pragma unroll
        for (int l = 0; l < 7; l++) {
            int j = (t << l) >> 7;
            hcv[l] = scl[l] * (tree[base[l] + 2 * j] - tree[base[l] + 2 * j + 1]);
        }
        float s4a = xrow[t * 8 + 0] + xrow[t * 8 + 1] + xrow[t * 8 + 2] + xrow[t * 8 + 3];
        float s4b = xrow[t * 8 + 4] + xrow[t * 8 + 5] + xrow[t * 8 + 6] + xrow[t * 8 + 7];
        hcv[7] = 0.3535533905932738f * (s4a - s4b);

#pragma unroll
        for (int l = 0; l < 8; l++) hc_lds[t * 8 + l] = hcv[l] * mask;
        idx_lds[t] = I;
    }
    __syncthreads();

    // ---- phase 2: output assembly (identical to R8) ----
    if (w < 12) {
        int third = w % 3;
        int grp = w / 3;
        int c = third * 64 + lane;

        float4 he[8];
        const float4* hg = (const float4*)haar_emb;
#pragma unroll
        for (int l = 0; l < 8; l++) he[l] = hg[l * 192 + c];

        const float4* pos4 = (const float4*)pos_emb;
        const float4* we4 = (const float4*)word_emb;
        float4* out4 = (float4*)out + (size_t)b * 128 * 192;

        for (int k = 0; k < 32; k += 2) {
            int row0 = grp * 32 + k;
            int row1 = row0 + 1;
            int iv0 = idx_lds[row0];
            int iv1 = idx_lds[row1];
            int ivc0 = iv0 < 0 ? 0 : iv0;
            int ivc1 = iv1 < 0 ? 0 : iv1;
            float msk0 = iv0 < 0 ? 0.f : 1.f;
            float msk1 = iv1 < 0 ? 0.f : 1.f;
            float4 p0 = pos4[row0 * 192 + c];
            float4 w0 = we4[(size_t)ivc0 * 192 + c];
            float4 h0a = *(const float4*)&hc_lds[row0 * 8];
            float4 h0b = *(const float4*)&hc_lds[row0 * 8 + 4];
            float4 p1 = pos4[row1 * 192 + c];
            float4 w1 = we4[(size_t)ivc1 * 192 + c];
            float4 h1a = *(const float4*)&hc_lds[row1 * 8];
            float4 h1b = *(const float4*)&hc_lds[row1 * 8 + 4];

            float4 acc0;
            acc0.x = fmaf(w0.x, msk0, p0.x);
            acc0.y = fmaf(w0.y, msk0, p0.y);
            acc0.z = fmaf(w0.z, msk0, p0.z);
            acc0.w = fmaf(w0.w, msk0, p0.w);
            float h0[8] = {h0a.x, h0a.y, h0a.z, h0a.w, h0b.x, h0b.y, h0b.z, h0b.w};
#pragma unroll
            for (int l = 0; l < 8; l++) {
                acc0.x += h0[l] * he[l].x;
                acc0.y += h0[l] * he[l].y;
                acc0.z += h0[l] * he[l].z;
                acc0.w += h0[l] * he[l].w;
            }
            {
                nfloat4 nv = {acc0.x, acc0.y, acc0.z, acc0.w};
                __builtin_nontemporal_store(nv, (nfloat4*)&out4[row0 * 192 + c]);
            }

            float4 acc1;
            acc1.x = fmaf(w1.x, msk1, p1.x);
            acc1.y = fmaf(w1.y, msk1, p1.y);
            acc1.z = fmaf(w1.z, msk1, p1.z);
            acc1.w = fmaf(w1.w, msk1, p1.w);
            float h1[8] = {h1a.x, h1a.y, h1a.z, h1a.w, h1b.x, h1b.y, h1b.z, h1b.w};
#pragma unroll
            for (int l = 0; l < 8; l++) {
                acc1.x += h1[l] * he[l].x;
                acc1.y += h1[l] * he[l].y;
                acc1.z += h1[l] * he[l].z;
                acc1.w += h1[l] * he[l].w;
            }
            {
                nfloat4 nv = {acc1.x, acc1.y, acc1.z, acc1.w};
                __builtin_nontemporal_store(nv, (nfloat4*)&out4[row1 * 192 + c]);
            }
        }
    }
}

extern "C" void kernel_launch(void* const* d_in, const int* in_sizes, int n_in,
                              void* d_out, int out_size, void* d_ws, size_t ws_size,
                              hipStream_t stream) {
    const float* X        = (const float*)d_in[0];
    const float* vocab    = (const float*)d_in[1];
    const float* word_emb = (const float*)d_in[2];
    const float* haar_emb = (const float*)d_in[3];
    const float* pos_emb  = (const float*)d_in[4];
    float* out = (float*)d_out;

    float* wsf  = (float*)d_ws;
    float* wc   = wsf;
    float* wstd = wsf + 8192;
    unsigned short* wcb = (unsigned short*)(wsf + 9216);

    hipLaunchKernelGGL(k0_vocab, dim3(4), dim3(256), 0, stream, vocab, wc, wstd, wcb);
    hipLaunchKernelGGL(k12_fused, dim3(256), dim3(1024), 0, stream,
                       X, wc, wstd, wcb, word_emb, haar_emb, pos_emb, out);
}

// Round 10
// 35.646 us; speedup vs baseline: 2.0434x; 1.1369x over previous
//
#include <hip/hip_runtime.h>
#include <math.h>

#define THRESH_ 0.95f

typedef float nfloat4 __attribute__((ext_vector_type(4)));
typedef __attribute__((ext_vector_type(8))) short short8v;
typedef __attribute__((ext_vector_type(16))) float f32x16;

__device__ __forceinline__ unsigned short f2bf_rne(float x) {
    unsigned u = __float_as_uint(x);
    u += 0x7fffu + ((u >> 16) & 1u);
    return (unsigned short)(u >> 16);
}

// Single fused kernel: vocab prep + MFMA-screened select + haar + output assembly.
// One block per batch row. Vocab stats are recomputed per block (1024 threads x
// 1 word each, ~50 VALU) straight into LDS — no k0, no workspace round-trip.
__global__ __launch_bounds__(1024) void k12_fused(const float* __restrict__ X,
                                                  const float* __restrict__ vocab,
                                                  const float* __restrict__ word_emb,
                                                  const float* __restrict__ haar_emb,
                                                  const float* __restrict__ pos_emb,
                                                  float* __restrict__ out) {
    __shared__ float4  wcl4[2048];    // fp32 centered vocab (32 KB)
    __shared__ short8v wcb_lds[1024]; // bf16 vocab (16 KB)
    __shared__ float   wsl[1024];     // word stds (4 KB)
    __shared__ float   xrow[1024];    // 4 KB
    __shared__ float   segf[1024];    // fp32 centered segments [128][8] (4 KB)
    __shared__ short8v segb[128];     // bf16 segments (2 KB)
    __shared__ float   sstd_l[128];
    __shared__ float   thr_l[128];    // 7.52f * sstd
    __shared__ float   stb[512];      // [4 chunks][128 segs]
    __shared__ int     sti[512];
    __shared__ float   stm[512];
    __shared__ float   tree[254];
    __shared__ float   hc_lds[1024];  // [128][8]
    __shared__ int     idx_lds[128];

    int t = threadIdx.x;
    int b = blockIdx.x;

    // ---- staging: X row + per-word vocab stats (identical arithmetic to old k0) ----
    xrow[t] = X[b * 1024 + t];
    {
        const float4* v4 = (const float4*)vocab + t * 2;
        float4 a = v4[0], bb = v4[1];
        float w[8] = {a.x, a.y, a.z, a.w, bb.x, bb.y, bb.z, bb.w};
        float s = 0.f;
#pragma unroll
        for (int c = 0; c < 8; c++) s += w[c];
        float mean = s * 0.125f;
        float ss = 0.f;
        float wcv[8];
#pragma unroll
        for (int c = 0; c < 8; c++) { wcv[c] = w[c] - mean; ss += wcv[c] * wcv[c]; }
        float sd = sqrtf(ss * 0.125f);
        float4 o0 = {wcv[0], wcv[1], wcv[2], wcv[3]};
        float4 o1 = {wcv[4], wcv[5], wcv[6], wcv[7]};
        wcl4[t * 2] = o0;
        wcl4[t * 2 + 1] = o1;
        wsl[t] = sd;
        union { uint4 q; unsigned short u[8]; } pk;
#pragma unroll
        for (int c = 0; c < 8; c++) pk.u[c] = f2bf_rne(wcv[c]);
        ((uint4*)wcb_lds)[t] = pk.q;
    }
    if (t < 512) { stb[t] = -INFINITY; sti[t] = -1; stm[t] = 0.f; }
    __syncthreads();

    // ---- segment stats (t < 128 only) ----
    if (t < 128) {
        float seg[8];
#pragma unroll
        for (int c = 0; c < 8; c++) seg[c] = xrow[t * 8 + c];
        float sum = 0.f;
#pragma unroll
        for (int c = 0; c < 8; c++) sum += seg[c];
        float mean = sum * 0.125f;
        float segc[8];
        float ss = 0.f;
#pragma unroll
        for (int c = 0; c < 8; c++) { segc[c] = seg[c] - mean; ss += segc[c] * segc[c]; }
        float sstd = sqrtf(ss * 0.125f);
        union { short8v v; unsigned short u[8]; } pk;
#pragma unroll
        for (int c = 0; c < 8; c++) { segf[t * 8 + c] = segc[c]; pk.u[c] = f2bf_rne(segc[c]); }
        segb[t] = pk.v;
        sstd_l[t] = sstd;
        thr_l[t] = 7.52f * sstd;
        tree[t] = sum;
    }
    __syncthreads();

    // ---- MFMA screen ----
    // Screen |acc_bf16| > 7.52*sstd*wsd has no false negatives vs the exact
    // condition |dot| >= 7.6000000238*RN(wsd*sstd) (bf16 error <= 0.032*sstd*wsd).
    // Rare candidates: exact fp32 dot (same op order as earlier rounds) +
    // f64 MID test + IEEE divide, applied in v-order per (chunk, segment).
    int w = t >> 6, lane = t & 63;
    {
        int sb = w & 3;        // seg-block (32 segments)
        int g = w >> 2;        // word-group (chunk): words [g*256, g*256+256)
        int half = lane >> 5;

        short8v af = {0, 0, 0, 0, 0, 0, 0, 0};
        if (lane < 32) af = segb[sb * 32 + lane];

        float thr_r[16];
#pragma unroll
        for (int i = 0; i < 16; i++) {
            int row = (i & 3) + 8 * (i >> 2) + 4 * half;
            thr_r[i] = thr_l[sb * 32 + row];
        }

        const double MID = 0x1.E66667p-1;
        for (int j = 0; j < 8; j++) {
            int wb = g * 8 + j;
            short8v bf = {0, 0, 0, 0, 0, 0, 0, 0};
            if (lane < 32) bf = wcb_lds[wb * 32 + lane];
            float wsd_c = wsl[wb * 32 + (lane & 31)];

            f32x16 accz = {0.f, 0.f, 0.f, 0.f, 0.f, 0.f, 0.f, 0.f,
                           0.f, 0.f, 0.f, 0.f, 0.f, 0.f, 0.f, 0.f};
            f32x16 acc = __builtin_amdgcn_mfma_f32_32x32x16_bf16(af, bf, accz, 0, 0, 0);

            bool anyp = false;
#pragma unroll
            for (int i = 0; i < 16; i++) anyp |= (fabsf(acc[i]) > thr_r[i] * wsd_c);

            if (__builtin_expect(anyp, 0)) {
#pragma unroll
                for (int i = 0; i < 16; i++) {
                    unsigned long long mi = __ballot(fabsf(acc[i]) > thr_r[i] * wsd_c);
                    while (mi) {
                        int src = __builtin_ctzll(mi);
                        mi &= mi - 1;
                        if (lane == src) {
                            int col = src & 31;
                            int seg_r = sb * 32 + (i & 3) + 8 * (i >> 2) + 4 * (src >> 5);
                            int v = wb * 32 + col;
                            float sst = sstd_l[seg_r];
                            float wsd = wsl[v];
                            const float* sc = &segf[seg_r * 8];
                            float4 wa = wcl4[v * 2];
                            float4 wbv = wcl4[v * 2 + 1];
                            // EXACT mul/fma order of previous rounds
                            float dot = sc[0] * wa.x + sc[1] * wa.y + sc[2] * wa.z + sc[3] * wa.w
                                      + sc[4] * wbv.x + sc[5] * wbv.y + sc[6] * wbv.z + sc[7] * wbv.w;
                            float cov = dot * 0.125f;
                            float denom = wsd * sst;
                            if ((double)fabsf(cov) >= MID * (double)denom) {
                                float c = (denom == 0.f) ? 0.f : cov / denom;
                                float a = fabsf(c);
                                int sidx = g * 128 + seg_r;
                                stm[sidx] = fmaxf(stm[sidx], a);
                                if (a > THRESH_ && stb[sidx] < a) { stb[sidx] = c; sti[sidx] = v; }
                            }
                        }
                    }
                }
            }
        }
    }
    __syncthreads();

    // ---- haar sum tree ----
    if (t < 64) tree[128 + t] = tree[2 * t] + tree[2 * t + 1];
    __syncthreads();
    if (t < 32) tree[192 + t] = tree[128 + 2 * t] + tree[128 + 2 * t + 1];
    __syncthreads();
    if (t < 16) tree[224 + t] = tree[192 + 2 * t] + tree[192 + 2 * t + 1];
    __syncthreads();
    if (t < 8) tree[240 + t] = tree[224 + 2 * t] + tree[224 + 2 * t + 1];
    __syncthreads();
    if (t < 4) tree[248 + t] = tree[240 + 2 * t] + tree[240 + 2 * t + 1];
    __syncthreads();
    if (t < 2) tree[252 + t] = tree[248 + 2 * t] + tree[248 + 2 * t + 1];
    __syncthreads();

    // ---- ordered 4-chunk merge + haar coefficients (t < 128) ----
    if (t < 128) {
        float Bb = stb[t];
        int I = sti[t];
#pragma unroll
        for (int p = 1; p < 4; p++) {
            float yb = stb[p * 128 + t];
            int yi = sti[p * 128 + t];
            float ym = stm[p * 128 + t];
            bool take = (yi != -1) && (!(Bb > THRESH_) || (ym > Bb));
            if (take) { Bb = yb; I = yi; }
        }
        float mask = (I >= 0) ? 1.f : 0.f;

        const int base[7] = {252, 248, 240, 224, 192, 128, 0};
        const float scl[7] = {0.03125f, 0.04419417382415922f, 0.0625f,
                              0.08838834764831843f, 0.125f,
                              0.17677669529663687f, 0.25f};
        float hcv[8];
#pragma unroll
        for (int l = 0; l < 7; l++) {
            int j = (t << l) >> 7;
            hcv[l] = scl[l] * (tree[base[l] + 2 * j] - tree[base[l] + 2 * j + 1]);
        }
        float s4a = xrow[t * 8 + 0] + xrow[t * 8 + 1] + xrow[t * 8 + 2] + xrow[t * 8 + 3];
        float s4b = xrow[t * 8 + 4] + xrow[t * 8 + 5] + xrow[t * 8 + 6] + xrow[t * 8 + 7];
        hcv[7] = 0.3535533905932738f * (s4a - s4b);

#pragma unroll
        for (int l = 0; l < 8; l++) hc_lds[t * 8 + l] = hcv[l] * mask;
        idx_lds[t] = I;
    }
    __syncthreads();

    // ---- phase 2: output assembly (identical to R8/R9) ----
    if (w < 12) {
        int third = w % 3;
        int grp = w / 3;
        int c = third * 64 + lane;

        float4 he[8];
        const float4* hg = (const float4*)haar_emb;
#pragma unroll
        for (int l = 0; l < 8; l++) he[l] = hg[l * 192 + c];

        const float4* pos4 = (const float4*)pos_emb;
        const float4* we4 = (const float4*)word_emb;
        float4* out4 = (float4*)out + (size_t)b * 128 * 192;

        for (int k = 0; k < 32; k += 2) {
            int row0 = grp * 32 + k;
            int row1 = row0 + 1;
            int iv0 = idx_lds[row0];
            int iv1 = idx_lds[row1];
            int ivc0 = iv0 < 0 ? 0 : iv0;
            int ivc1 = iv1 < 0 ? 0 : iv1;
            float msk0 = iv0 < 0 ? 0.f : 1.f;
            float msk1 = iv1 < 0 ? 0.f : 1.f;
            float4 p0 = pos4[row0 * 192 + c];
            float4 w0 = we4[(size_t)ivc0 * 192 + c];
            float4 h0a = *(const float4*)&hc_lds[row0 * 8];
            float4 h0b = *(const float4*)&hc_lds[row0 * 8 + 4];
            float4 p1 = pos4[row1 * 192 + c];
            float4 w1 = we4[(size_t)ivc1 * 192 + c];
            float4 h1a = *(const float4*)&hc_lds[row1 * 8];
            float4 h1b = *(const float4*)&hc_lds[row1 * 8 + 4];

            float4 acc0;
            acc0.x = fmaf(w0.x, msk0, p0.x);
            acc0.y = fmaf(w0.y, msk0, p0.y);
            acc0.z = fmaf(w0.z, msk0, p0.z);
            acc0.w = fmaf(w0.w, msk0, p0.w);
            float h0[8] = {h0a.x, h0a.y, h0a.z, h0a.w, h0b.x, h0b.y, h0b.z, h0b.w};
#pragma unroll
            for (int l = 0; l < 8; l++) {
                acc0.x += h0[l] * he[l].x;
                acc0.y += h0[l] * he[l].y;
                acc0.z += h0[l] * he[l].z;
                acc0.w += h0[l] * he[l].w;
            }
            {
                nfloat4 nv = {acc0.x, acc0.y, acc0.z, acc0.w};
                __builtin_nontemporal_store(nv, (nfloat4*)&out4[row0 * 192 + c]);
            }

            float4 acc1;
            acc1.x = fmaf(w1.x, msk1, p1.x);
            acc1.y = fmaf(w1.y, msk1, p1.y);
            acc1.z = fmaf(w1.z, msk1, p1.z);
            acc1.w = fmaf(w1.w, msk1, p1.w);
            float h1[8] = {h1a.x, h1a.y, h1a.z, h1a.w, h1b.x, h1b.y, h1b.z, h1b.w};
#pragma unroll
            for (int l = 0; l < 8; l++) {
                acc1.x += h1[l] * he[l].x;
                acc1.y += h1[l] * he[l].y;
                acc1.z += h1[l] * he[l].z;
                acc1.w += h1[l] * he[l].w;
            }
            {
                nfloat4 nv = {acc1.x, acc1.y, acc1.z, acc1.w};
                __builtin_nontemporal_store(nv, (nfloat4*)&out4[row1 * 192 + c]);
            }
        }
    }
}

extern "C" void kernel_launch(void* const* d_in, const int* in_sizes, int n_in,
                              void* d_out, int out_size, void* d_ws, size_t ws_size,
                              hipStream_t stream) {
    const float* X        = (const float*)d_in[0];
    const float* vocab    = (const float*)d_in[1];
    const float* word_emb = (const float*)d_in[2];
    const float* haar_emb = (const float*)d_in[3];
    const float* pos_emb  = (const float*)d_in[4];
    float* out = (float*)d_out;

    hipLaunchKernelGGL(k12_fused, dim3(256), dim3(1024), 0, stream,
                       X, vocab, word_emb, haar_emb, pos_emb, out);
}